// Round 3
// baseline (1035.688 us; speedup 1.0000x reference)
//
#include <hip/hip_runtime.h>

#define NROWS 500000
#define DD 128
#define NSTACK 12
#define BNEPS 1e-3f
#define NCOL 50           // 48 layer-unit columns + 2 final-logit columns
#define WXSTRIDE 52       // pad 50 -> 52 floats: 208B, divisible by 16 (b128-aligned rows)
#define RPT 4             // rows per thread

typedef float v2f __attribute__((ext_vector_type(2)));
typedef float v4f __attribute__((ext_vector_type(4)));

// R rows per thread; all weights staged in LDS; one weight read feeds RPT rows.
__global__ __launch_bounds__(256, 2) void predict_kernel(
    const float* __restrict__ x,
    const float* __restrict__ w0,  const float* __restrict__ w1,
    const float* __restrict__ w2,  const float* __restrict__ w3,
    const float* __restrict__ w4,  const float* __restrict__ w5,
    const float* __restrict__ w6,  const float* __restrict__ w7,
    const float* __restrict__ w8,  const float* __restrict__ w9,
    const float* __restrict__ w10, const float* __restrict__ w11,
    const float* __restrict__ gamma_, const float* __restrict__ beta_,
    const float* __restrict__ mean_,  const float* __restrict__ var_,
    const float* __restrict__ wf,     const float* __restrict__ bf,
    float* __restrict__ out)
{
    // ---- LDS staging ----
    __shared__ __align__(16) float WX[DD * WXSTRIDE]; // [k][col] transposed x-weights
    __shared__ __align__(16) float WH[1056];          // history weights, per-layer packed
    __shared__ __align__(16) float WFY[96];           // wf rows 0..47 (y-history part)
    __shared__ float SC[48];
    __shared__ float SH[48];
    __shared__ float BF[2];

    const int tid = threadIdx.x;
    const float* ws[NSTACK] = {w0,w1,w2,w3,w4,w5,w6,w7,w8,w9,w10,w11};

    for (int idx = tid; idx < DD * NCOL; idx += 256) {
        const int k = idx / NCOL;
        const int c = idx - k * NCOL;
        float v;
        if (c < 48) {
            const int i = c >> 2, u = c & 3;
            v = ws[i][16 * i + 4 * k + u];
        } else {
            v = wf[96 + 2 * k + (c - 48)];
        }
        WX[k * WXSTRIDE + c] = v;
    }
#pragma unroll
    for (int i = 1; i < NSTACK; ++i) {
        const int off = 8 * i * (i - 1);
        for (int idx = tid; idx < 16 * i; idx += 256) WH[off + idx] = ws[i][idx];
    }
    for (int idx = tid; idx < 96; idx += 256) WFY[idx] = wf[idx];
    if (tid < 48) {
        const float sc = gamma_[tid] / sqrtf(var_[tid] + BNEPS);
        SC[tid] = sc;
        SH[tid] = beta_[tid] - mean_[tid] * sc;
    }
    if (tid < 2) BF[tid] = bf[tid];
    __syncthreads();

    // ---- rows handled by this thread ----
    const int base = blockIdx.x * (256 * RPT) + tid;
    int  rowc [RPT];
    bool valid[RPT];
#pragma unroll
    for (int r = 0; r < RPT; ++r) {
        const int rr = base + 256 * r;
        valid[r] = rr < NROWS;
        rowc[r]  = valid[r] ? rr : (NROWS - 1);   // clamp: harmless duplicate reads
    }
    const v4f* __restrict__ xv[RPT];
#pragma unroll
    for (int r = 0; r < RPT; ++r) xv[r] = (const v4f*)(x + (size_t)rowc[r] * DD);

    // ---- Phase 1: x projection onto 50 columns, RPT rows at once ----
    v2f T[RPT][25];
#pragma unroll
    for (int r = 0; r < RPT; ++r)
#pragma unroll
        for (int j = 0; j < 25; ++j) T[r][j] = (v2f){0.0f, 0.0f};

    for (int kk = 0; kk < DD / 4; ++kk) {
        v4f xc[RPT];
#pragma unroll
        for (int r = 0; r < RPT; ++r) xc[r] = xv[r][kk];
#pragma unroll
        for (int c = 0; c < 4; ++c) {
            const float* wrow = &WX[(kk * 4 + c) * WXSTRIDE];
#pragma unroll
            for (int j = 0; j < NSTACK; ++j) {
                const v4f w = *(const v4f*)(wrow + 4 * j);   // one broadcast read, RPT uses
                const v2f wlo = {w.x, w.y};
                const v2f whi = {w.z, w.w};
#pragma unroll
                for (int r = 0; r < RPT; ++r) {
                    const float xk = xc[r][c];
                    T[r][2 * j]     += xk * wlo;
                    T[r][2 * j + 1] += xk * whi;
                }
            }
            const v2f w2 = *(const v2f*)(wrow + 48);
#pragma unroll
            for (int r = 0; r < RPT; ++r) T[r][24] += xc[r][c] * w2;
        }
    }

    // ---- Phases 2+3 per row ----
#pragma unroll
    for (int r = 0; r < RPT; ++r) {
        float y[NSTACK * 4];
#pragma unroll
        for (int i = 0; i < NSTACK; ++i) {
            float acc0 = T[r][2 * i].x, acc1 = T[r][2 * i].y;
            float acc2 = T[r][2 * i + 1].x, acc3 = T[r][2 * i + 1].y;
            const float* wh = &WH[8 * i * (i - 1)];
#pragma unroll
            for (int m = 0; m < 4 * i; ++m) {
                const float hv = y[(i - 1 - (m >> 2)) * 4 + (m & 3)];
                const v4f wv = *(const v4f*)(wh + 4 * m);
                acc0 += hv * wv.x; acc1 += hv * wv.y;
                acc2 += hv * wv.z; acc3 += hv * wv.w;
            }
            const float* sc = &SC[4 * i];
            const float* sh = &SH[4 * i];
            float r0 = acc0 * sc[0] + sh[0];
            float r1 = acc1 * sc[1] + sh[1];
            float r2 = acc2 * sc[2] + sh[2];
            float r3 = acc3 * sc[3] + sh[3];
            y[i * 4 + 0] = r0 > 0.0f ? r0 : 0.0f;
            y[i * 4 + 1] = r1 > 0.0f ? r1 : 0.0f;
            y[i * 4 + 2] = r2 > 0.0f ? r2 : 0.0f;
            y[i * 4 + 3] = r3 > 0.0f ? r3 : 0.0f;
        }

        float l0 = T[r][24].x + BF[0];
        float l1 = T[r][24].y + BF[1];
#pragma unroll
        for (int m = 0; m < 48; ++m) {
            const float hv = y[(11 - (m >> 2)) * 4 + (m & 3)];
            const v2f wv = *(const v2f*)(&WFY[2 * m]);
            l0 += hv * wv.x;
            l1 += hv * wv.y;
        }

        const float mx = fmaxf(l0, l1);
        const float e0 = __expf(l0 - mx);
        const float e1 = __expf(l1 - mx);
        const float inv = 1.0f / (e0 + e1);
        if (valid[r]) {
            *(v2f*)(out + (size_t)rowc[r] * 2) = (v2f){e0 * inv, e1 * inv};
        }
    }
}

extern "C" void kernel_launch(void* const* d_in, const int* in_sizes, int n_in,
                              void* d_out, int out_size, void* d_ws, size_t ws_size,
                              hipStream_t stream) {
    const float* x   = (const float*)d_in[0];
    const float* w0  = (const float*)d_in[1];
    const float* w1  = (const float*)d_in[2];
    const float* w2  = (const float*)d_in[3];
    const float* w3  = (const float*)d_in[4];
    const float* w4  = (const float*)d_in[5];
    const float* w5  = (const float*)d_in[6];
    const float* w6  = (const float*)d_in[7];
    const float* w7  = (const float*)d_in[8];
    const float* w8  = (const float*)d_in[9];
    const float* w9  = (const float*)d_in[10];
    const float* w10 = (const float*)d_in[11];
    const float* w11 = (const float*)d_in[12];
    const float* gm  = (const float*)d_in[13];
    const float* bt  = (const float*)d_in[14];
    const float* mn  = (const float*)d_in[15];
    const float* vr  = (const float*)d_in[16];
    const float* wf  = (const float*)d_in[17];
    const float* bf  = (const float*)d_in[18];
    float* out = (float*)d_out;

    const int rows_per_block = 256 * RPT;
    dim3 block(256);
    dim3 grid((NROWS + rows_per_block - 1) / rows_per_block);
    hipLaunchKernelGGL(predict_kernel, grid, block, 0, stream,
                       x, w0, w1, w2, w3, w4, w5, w6, w7, w8, w9, w10, w11,
                       gm, bt, mn, vr, wf, bf, out);
}

// Round 4
// 419.237 us; speedup vs baseline: 2.4704x; 2.4704x over previous
//
#include <hip/hip_runtime.h>

#define NROWS 500000
#define DD 128
#define NSTACK 12
#define BNEPS 1e-3f
#define NCOL 50
#define TRS 50            // Trow stride in floats (200B: 8B-aligned rows)

typedef float  v2f    __attribute__((ext_vector_type(2)));
typedef float  v4f    __attribute__((ext_vector_type(4)));
typedef float  f32x4  __attribute__((ext_vector_type(4)));
typedef __bf16 bf16x8 __attribute__((ext_vector_type(8)));

__device__ __forceinline__ unsigned short f2bf_rn(float f) {
    unsigned u = __float_as_uint(f);
    return (unsigned short)((u + 0x7FFFu + ((u >> 16) & 1u)) >> 16);
}

// Per block: 4 waves x 64 rows = 256 rows.
// Phase 1: [256x128]@[128x64] GEMM via mfma_f32_16x16x32_bf16.
//   A: global fp32 -> bf16 in-register. B: bf16 pre-swizzled in LDS fragment order.
// Phase 1.5: C-frag -> LDS transpose (wave-private) so lane owns one row.
// Phase 2: sequential 12-layer recurrence; weights via scalar K$ path (s_load).
// Phase 3: final logits + softmax.
__global__ __launch_bounds__(256, 2) void predict_kernel(
    const float* __restrict__ x,
    const float* __restrict__ w0,  const float* __restrict__ w1,
    const float* __restrict__ w2,  const float* __restrict__ w3,
    const float* __restrict__ w4,  const float* __restrict__ w5,
    const float* __restrict__ w6,  const float* __restrict__ w7,
    const float* __restrict__ w8,  const float* __restrict__ w9,
    const float* __restrict__ w10, const float* __restrict__ w11,
    const float* __restrict__ gamma_, const float* __restrict__ beta_,
    const float* __restrict__ mean_,  const float* __restrict__ var_,
    const float* __restrict__ wf,     const float* __restrict__ bf,
    float* __restrict__ out)
{
    __shared__ __align__(16) union {
        unsigned short bsw[4][4][64][8];   // [kt][nt][lane][j], 16 KB
        float          trow[256 * TRS];    // 51.2 KB
    } sh;
    __shared__ __align__(16) float SC[48];
    __shared__ __align__(16) float SH[48];
    __shared__ float BF2[2];

    const int tid = threadIdx.x;
    const float* ws[NSTACK] = {w0,w1,w2,w3,w4,w5,w6,w7,w8,w9,w10,w11};

    // ---- stage B fragments (bf16, fragment-order) ----
    // zero everything first (covers pad cols 50..63)
    for (int idx = tid; idx < 1024; idx += 256)
        ((f32x4*)&sh.bsw[0][0][0][0])[idx] = (f32x4){0.f, 0.f, 0.f, 0.f};
    __syncthreads();

    // layer columns n = 4i+u <- ws[i][16i + 4k + u]
#pragma unroll
    for (int i = 0; i < NSTACK; ++i) {
        const float* wsi = ws[i];
        for (int e = tid; e < 512; e += 256) {       // e = 4k+u
            const int k = e >> 2, u = e & 3;
            const int n = 4 * i + u;
            const int kt = k >> 5, q = (k >> 3) & 3, j = k & 7;
            const int nt = n >> 4, lane = q * 16 + (n & 15);
            sh.bsw[kt][nt][lane][j] = f2bf_rn(wsi[16 * i + e]);
        }
    }
    // logit columns n = 48,49 <- wf[96 + 2k + u]
    {
        const int e = tid;                            // e = 2k+u, 256 elements
        const int k = e >> 1, u = e & 1;
        const int n = 48 + u;
        const int kt = k >> 5, q = (k >> 3) & 3, j = k & 7;
        const int lane = q * 16 + (n & 15);
        sh.bsw[kt][3][lane][j] = f2bf_rn(wf[96 + e]);
    }
    if (tid < 48) {
        const float sc = gamma_[tid] * __frsqrt_rn(var_[tid] + BNEPS);
        SC[tid] = sc;
        SH[tid] = beta_[tid] - mean_[tid] * sc;
    }
    if (tid < 2) BF2[tid] = bf[tid];
    __syncthreads();

    // ---- Phase 1: MFMA GEMM ----
    const int lane = tid & 63;
    const int wv   = tid >> 6;
    const int rowbase = blockIdx.x * 256 + wv * 64;
    const int m = lane & 15;
    const int q = lane >> 4;

    const float* arow[4];
#pragma unroll
    for (int mt = 0; mt < 4; ++mt) {
        int r = rowbase + mt * 16 + m;
        if (r > NROWS - 1) r = NROWS - 1;             // tail clamp (stores predicated)
        arow[mt] = x + (size_t)r * DD + q * 8;
    }

    f32x4 acc[4][4];
#pragma unroll
    for (int mt = 0; mt < 4; ++mt)
#pragma unroll
        for (int nt = 0; nt < 4; ++nt) acc[mt][nt] = (f32x4){0.f, 0.f, 0.f, 0.f};

#pragma unroll
    for (int kt = 0; kt < 4; ++kt) {
        bf16x8 bfrag[4];
#pragma unroll
        for (int nt = 0; nt < 4; ++nt)
            bfrag[nt] = *(const bf16x8*)&sh.bsw[kt][nt][lane][0];   // ds_read_b128
#pragma unroll
        for (int mt = 0; mt < 4; ++mt) {
            const v4f a0 = *(const v4f*)(arow[mt] + kt * 32);
            const v4f a1 = *(const v4f*)(arow[mt] + kt * 32 + 4);
            union { unsigned short us[8]; bf16x8 bv; } au;
#pragma unroll
            for (int e = 0; e < 4; ++e) {
                au.us[e]     = f2bf_rn(a0[e]);
                au.us[4 + e] = f2bf_rn(a1[e]);
            }
#pragma unroll
            for (int nt = 0; nt < 4; ++nt)
                acc[mt][nt] = __builtin_amdgcn_mfma_f32_16x16x32_bf16(
                    au.bv, bfrag[nt], acc[mt][nt], 0, 0, 0);
        }
    }

    __syncthreads();   // all waves done with bsw before trow overwrites it

    // ---- Phase 1.5: C-frag -> row-major LDS (wave-private region) ----
    // C/D layout: col = lane&15, row = (lane>>4)*4 + reg   [m89/m91]
    float* tr = &sh.trow[wv * 64 * TRS];
#pragma unroll
    for (int mt = 0; mt < 4; ++mt)
#pragma unroll
        for (int nt = 0; nt < 4; ++nt) {
            const int c = nt * 16 + m;
            if (c < NCOL) {
#pragma unroll
                for (int r = 0; r < 4; ++r)
                    tr[(mt * 16 + q * 4 + r) * TRS + c] = acc[mt][nt][r];
            }
        }

    // ---- Phase 2: per-lane recurrence (lane owns row rowbase+lane) ----
    const float* myT = &sh.trow[(wv * 64 + lane) * TRS];
    float T[NCOL];
#pragma unroll
    for (int j = 0; j < NCOL / 2; ++j) {
        const v2f t = *(const v2f*)(myT + 2 * j);     // ds_read_b64
        T[2 * j] = t.x; T[2 * j + 1] = t.y;
    }

    float y[NSTACK * 4];
#pragma unroll
    for (int i = 0; i < NSTACK; ++i) {
        float a0 = T[4 * i + 0], a1 = T[4 * i + 1];
        float a2 = T[4 * i + 2], a3 = T[4 * i + 3];
        const float* wsi = ws[i];
#pragma unroll
        for (int mr = 0; mr < 4 * i; ++mr) {          // uniform idx -> s_load (K$)
            const float hv = y[(i - 1 - (mr >> 2)) * 4 + (mr & 3)];
            a0 += hv * wsi[4 * mr + 0];
            a1 += hv * wsi[4 * mr + 1];
            a2 += hv * wsi[4 * mr + 2];
            a3 += hv * wsi[4 * mr + 3];
        }
        const v4f scv = *(const v4f*)&SC[4 * i];
        const v4f shv = *(const v4f*)&SH[4 * i];
        const float r0 = a0 * scv.x + shv.x;
        const float r1 = a1 * scv.y + shv.y;
        const float r2 = a2 * scv.z + shv.z;
        const float r3 = a3 * scv.w + shv.w;
        y[4 * i + 0] = r0 > 0.f ? r0 : 0.f;
        y[4 * i + 1] = r1 > 0.f ? r1 : 0.f;
        y[4 * i + 2] = r2 > 0.f ? r2 : 0.f;
        y[4 * i + 3] = r3 > 0.f ? r3 : 0.f;
    }

    // ---- Phase 3: final logits + softmax ----
    float l0 = T[48] + BF2[0];
    float l1 = T[49] + BF2[1];
#pragma unroll
    for (int mr = 0; mr < 48; ++mr) {                 // uniform idx -> s_load (K$)
        const float hv = y[(11 - (mr >> 2)) * 4 + (mr & 3)];
        l0 += hv * wf[2 * mr + 0];
        l1 += hv * wf[2 * mr + 1];
    }

    const float mx = fmaxf(l0, l1);
    const float e0 = __expf(l0 - mx);
    const float e1 = __expf(l1 - mx);
    const float inv = 1.0f / (e0 + e1);

    const int row = rowbase + lane;
    if (row < NROWS)
        *(v2f*)(out + (size_t)row * 2) = (v2f){e0 * inv, e1 * inv};
}

extern "C" void kernel_launch(void* const* d_in, const int* in_sizes, int n_in,
                              void* d_out, int out_size, void* d_ws, size_t ws_size,
                              hipStream_t stream) {
    const float* x   = (const float*)d_in[0];
    const float* w0  = (const float*)d_in[1];
    const float* w1  = (const float*)d_in[2];
    const float* w2  = (const float*)d_in[3];
    const float* w3  = (const float*)d_in[4];
    const float* w4  = (const float*)d_in[5];
    const float* w5  = (const float*)d_in[6];
    const float* w6  = (const float*)d_in[7];
    const float* w7  = (const float*)d_in[8];
    const float* w8  = (const float*)d_in[9];
    const float* w9  = (const float*)d_in[10];
    const float* w10 = (const float*)d_in[11];
    const float* w11 = (const float*)d_in[12];
    const float* gm  = (const float*)d_in[13];
    const float* bt  = (const float*)d_in[14];
    const float* mn  = (const float*)d_in[15];
    const float* vr  = (const float*)d_in[16];
    const float* wf  = (const float*)d_in[17];
    const float* bf  = (const float*)d_in[18];
    float* out = (float*)d_out;

    dim3 block(256);
    dim3 grid((NROWS + 255) / 256);   // 256 rows per block
    hipLaunchKernelGGL(predict_kernel, grid, block, 0, stream,
                       x, w0, w1, w2, w3, w4, w5, w6, w7, w8, w9, w10, w11,
                       gm, bt, mn, vr, wf, bf, out);
}